// Round 1
// baseline (357.789 us; speedup 1.0000x reference)
//
#include <hip/hip_runtime.h>
#include <math.h>

// Problem constants (from reference)
#define B_ROWS 65536
#define C_COLS 1024
#define GRID_BLOCKS 2048
#define BLOCK_THREADS 256
#define WAVES_PER_BLOCK (BLOCK_THREADS / 64)

__device__ __forceinline__ float softplus(float x) {
    // log1p(exp(x)), numerically stable for large |x|
    float ax = fabsf(x);
    return fmaxf(x, 0.0f) + log1pf(expf(-ax));
}

__global__ __launch_bounds__(BLOCK_THREADS) void rank_loss_partial(
        const float* __restrict__ scores,
        const int* __restrict__ labels,
        double* __restrict__ partials) {
    const int waveId = threadIdx.x >> 6;
    const int lane = threadIdx.x & 63;
    const int globalWave = blockIdx.x * WAVES_PER_BLOCK + waveId;
    const int totalWaves = GRID_BLOCKS * WAVES_PER_BLOCK;

    const float MARGIN_POS = 2.5f;
    const float MARGIN_NEG = 0.5f;
    const float GAMMA = 2.0f;

    double acc = 0.0;
    for (int row = globalWave; row < B_ROWS; row += totalWaves) {
        const int label = labels[row];
        const float4* __restrict__ rowp =
            (const float4*)(scores + (size_t)row * C_COLS);

        float m = -INFINITY;     // max over negative classes
        float spos = -INFINITY;  // positive score (only the owning lane finds it)

        #pragma unroll
        for (int it = 0; it < 4; ++it) {
            const int c4 = it * 64 + lane;  // float4 index within row (coalesced)
            float4 v = rowp[c4];
            const int j = label - c4 * 4;   // position of label within this float4, if any
            if (j >= 0 && j < 4) {
                float vv[4] = {v.x, v.y, v.z, v.w};
                spos = vv[j];
                vv[j] = -INFINITY;          // exclude positive from the max
                v.x = vv[0]; v.y = vv[1]; v.z = vv[2]; v.w = vv[3];
            }
            m = fmaxf(m, fmaxf(fmaxf(v.x, v.y), fmaxf(v.z, v.w)));
        }

        // wave-level max reduce (64 lanes)
        #pragma unroll
        for (int off = 32; off > 0; off >>= 1) {
            m    = fmaxf(m,    __shfl_down(m,    off, 64));
            spos = fmaxf(spos, __shfl_down(spos, off, 64));
        }

        if (lane == 0) {
            float sneg = (label == 0) ? 0.0f : m;
            float lp = softplus(GAMMA * (MARGIN_POS - spos));
            float ln = softplus(GAMMA * (MARGIN_NEG + sneg));
            acc += (double)(lp + ln);
        }
    }

    // block reduction of per-wave accumulators (only lane 0 of each wave holds data)
    __shared__ double sacc[WAVES_PER_BLOCK];
    if (lane == 0) sacc[waveId] = acc;
    __syncthreads();
    if (threadIdx.x == 0) {
        double s = 0.0;
        #pragma unroll
        for (int i = 0; i < WAVES_PER_BLOCK; ++i) s += sacc[i];
        partials[blockIdx.x] = s;
    }
}

__global__ __launch_bounds__(256) void rank_loss_final(
        const double* __restrict__ partials, float* __restrict__ out) {
    __shared__ double sdata[256];
    double s = 0.0;
    for (int i = threadIdx.x; i < GRID_BLOCKS; i += 256) s += partials[i];
    sdata[threadIdx.x] = s;
    __syncthreads();
    #pragma unroll
    for (int off = 128; off > 0; off >>= 1) {
        if (threadIdx.x < off) sdata[threadIdx.x] += sdata[threadIdx.x + off];
        __syncthreads();
    }
    if (threadIdx.x == 0) out[0] = (float)(sdata[0] / (double)B_ROWS);
}

extern "C" void kernel_launch(void* const* d_in, const int* in_sizes, int n_in,
                              void* d_out, int out_size, void* d_ws, size_t ws_size,
                              hipStream_t stream) {
    const float* scores = (const float*)d_in[0];
    const int* labels = (const int*)d_in[1];
    float* out = (float*)d_out;
    double* partials = (double*)d_ws;  // GRID_BLOCKS doubles = 16 KB

    rank_loss_partial<<<GRID_BLOCKS, BLOCK_THREADS, 0, stream>>>(scores, labels, partials);
    rank_loss_final<<<1, 256, 0, stream>>>(partials, out);
}